// Round 5
// baseline (180.022 us; speedup 1.0000x reference)
//
#include <hip/hip_runtime.h>
#include <stdint.h>

#define Bn 4
#define An 3
#define Hn 168
#define Wn 256
#define Mn 32
#define HWn (Hn*Wn)
#define Nn (HWn*An)          // 129024
#define POS_CAP 8192
#define BND_CAP 2048
#define NPERIM 256
#define NPOSMAX 128
#define FG_THR 0.7f
#define BG_THR 0.3f
#define BETA (1.0f/9.0f)

// ---- workspace layout (uint32 word offsets) ----
#define OFF_KEYS   0            // Bn*2 (written in k0, outside zero range)
#define OFF_COLMAX 8            // Bn*Mn = 128 (float bits, atomicMax)
#define OFF_POSCNT 136          // Bn
#define OFF_BNDCNT 140          // Bn
#define OFF_BOUND  144          // Bn (int32, -1 = all negatives selected)
#define OFF_NEED   148          // Bn
#define OFF_COUNT  152          // 1 (uint)
#define OFF_CLS    153          // 1 (float bits)
#define OFF_REG    154          // 1 (float bits)
#define OFF_DONE   155          // 1 (uint, k4 completion counter)
#define OFF_HIST   160          // Bn*1024 = 4096 -> end 4256
#define ZERO_BEG   8
#define ZERO_END   4256
#define OFF_PACK   4256         // Bn*Nn  (m | cat<<24)   -> 520352
#define OFF_PLIST  520352       // Bn*POS_CAP*2           -> 585888
#define OFF_BLIST  585888       // Bn*BND_CAP*2           -> 602272

// ------------------- threefry2x32 (20 rounds) -------------------
__device__ __forceinline__ uint32_t rotl32(uint32_t v, int n) { return (v << n) | (v >> (32 - n)); }

__device__ __forceinline__ void tf2x32(uint32_t k0, uint32_t k1, uint32_t x0, uint32_t x1,
                                       uint32_t& o0, uint32_t& o1) {
    uint32_t k2 = k0 ^ k1 ^ 0x1BD11BDAu;
    x0 += k0; x1 += k1;
    x0 += x1; x1 = rotl32(x1, 13); x1 ^= x0;
    x0 += x1; x1 = rotl32(x1, 15); x1 ^= x0;
    x0 += x1; x1 = rotl32(x1, 26); x1 ^= x0;
    x0 += x1; x1 = rotl32(x1, 6);  x1 ^= x0;
    x0 += k1; x1 += k2 + 1u;
    x0 += x1; x1 = rotl32(x1, 17); x1 ^= x0;
    x0 += x1; x1 = rotl32(x1, 29); x1 ^= x0;
    x0 += x1; x1 = rotl32(x1, 16); x1 ^= x0;
    x0 += x1; x1 = rotl32(x1, 24); x1 ^= x0;
    x0 += k2; x1 += k0 + 2u;
    x0 += x1; x1 = rotl32(x1, 13); x1 ^= x0;
    x0 += x1; x1 = rotl32(x1, 15); x1 ^= x0;
    x0 += x1; x1 = rotl32(x1, 26); x1 ^= x0;
    x0 += x1; x1 = rotl32(x1, 6);  x1 ^= x0;
    x0 += k0; x1 += k1 + 3u;
    x0 += x1; x1 = rotl32(x1, 17); x1 ^= x0;
    x0 += x1; x1 = rotl32(x1, 29); x1 ^= x0;
    x0 += x1; x1 = rotl32(x1, 16); x1 ^= x0;
    x0 += x1; x1 = rotl32(x1, 24); x1 ^= x0;
    x0 += k1; x1 += k2 + 4u;
    x0 += x1; x1 = rotl32(x1, 13); x1 ^= x0;
    x0 += x1; x1 = rotl32(x1, 15); x1 ^= x0;
    x0 += x1; x1 = rotl32(x1, 26); x1 ^= x0;
    x0 += x1; x1 = rotl32(x1, 6);  x1 ^= x0;
    x0 += k2; x1 += k0 + 5u;
    o0 = x0; o1 = x1;
}

__device__ __forceinline__ uint32_t rng_m23(uint32_t k0, uint32_t k1, uint32_t i) {
    uint32_t o0, o1;
    tf2x32(k0, k1, 0u, i, o0, o1);
    return (o0 ^ o1) >> 9;
}

// ------------------- IoU (shared by k1/k2 for bit-identical values) -------------------
__device__ __forceinline__ float iou_one(float a0, float a1, float a2, float a3,
                                         float t0, float t1, float t2, float t3) {
    float xtl = fmaxf(a0, t0), ytl = fmaxf(a1, t1);
    float xrb = fminf(a2, t2), yrb = fminf(a3, t3);
    float iw = fmaxf(xrb - xtl + 1.0f, 0.0f);
    float ih = fmaxf(yrb - ytl + 1.0f, 0.0f);
    float inter = iw * ih;
    float area1 = (a2 - a0 + 1.0f) * (a3 - a1 + 1.0f);
    float area2 = (t2 - t0 + 1.0f) * (t3 - t1 + 1.0f);
    return inter * __builtin_amdgcn_rcpf(area1 + area2 - inter);
}

// ------------------- K0: zero control region, derive per-image keys -------------------
__global__ void k0_init(uint32_t* __restrict__ ws) {
    int t = blockIdx.x * blockDim.x + threadIdx.x;
    for (int j = ZERO_BEG + t; j < ZERO_END; j += gridDim.x * blockDim.x) ws[j] = 0u;
    if (t == 0) {
        for (int b = 0; b < Bn; ++b) {
            uint32_t o0, o1;
            tf2x32(0u, 42u, 0u, (uint32_t)b, o0, o1);
            ws[OFF_KEYS + 2*b] = o0; ws[OFF_KEYS + 2*b + 1] = o1;
        }
    }
}

// ------------------- K1: per-target column max IoU -------------------
// APT=4: 126 blocks/image -> 504 blocks total (2 blocks/CU, 8 waves/CU) —
// balances shuffle-reduction amortization against wave residency (APT=8 at
// 252 blocks was 1 wave/SIMD: zero latency hiding, ~40us).
#define K1_APT 4
#define K1_BLOCKS 126
#define K1_STRIDE (K1_BLOCKS * 256)    // 32256
__global__ void __launch_bounds__(256) k1_colmax(const float* __restrict__ anchors,
                                                 const float* __restrict__ targets,
                                                 uint32_t* __restrict__ ws) {
    int b = blockIdx.y;
    __shared__ float part[4][Mn];
    int base = blockIdx.x * 256 + threadIdx.x;
    float4 a[K1_APT];
    #pragma unroll
    for (int k = 0; k < K1_APT; ++k)
        a[k] = ((const float4*)anchors)[b * Nn + base + k * K1_STRIDE];
    float cm[Mn];
    #pragma unroll 4
    for (int t = 0; t < Mn; ++t) {
        float4 tv = ((const float4*)targets)[b * Mn + t];
        float m0 = 0.0f;
        #pragma unroll
        for (int k = 0; k < K1_APT; ++k)
            m0 = fmaxf(m0, iou_one(a[k].x, a[k].y, a[k].z, a[k].w, tv.x, tv.y, tv.z, tv.w));
        cm[t] = m0;
    }
    #pragma unroll
    for (int t = 0; t < Mn; ++t) {
        #pragma unroll
        for (int o = 32; o > 0; o >>= 1) cm[t] = fmaxf(cm[t], __shfl_xor(cm[t], o, 64));
    }
    int wid = threadIdx.x >> 6, lane = threadIdx.x & 63;
    if (lane == 0) {
        #pragma unroll
        for (int t = 0; t < Mn; ++t) part[wid][t] = cm[t];
    }
    __syncthreads();
    if (threadIdx.x < Mn) {
        float v = fmaxf(fmaxf(part[0][threadIdx.x], part[1][threadIdx.x]),
                        fmaxf(part[2][threadIdx.x], part[3][threadIdx.x]));
        atomicMax(&ws[OFF_COLMAX + b * Mn + threadIdx.x], __float_as_uint(v));
    }
}

// ------------------- K2: categorize, RNG, histogram, positive list -------------------
// APT=2: 252 blocks/image -> 1008 blocks (4 blocks/CU, ~16 waves/CU) —
// R4's APT=4 (504 blocks) dropped occupancy to 15% and stalled on latency.
#define K2_APT 2
#define K2_BLOCKS 252
#define K2_STRIDE (K2_BLOCKS * 256)    // 64512
__global__ void __launch_bounds__(256) k2_cat(const float* __restrict__ anchors,
                                              const float* __restrict__ targets,
                                              const float* __restrict__ sizes,
                                              uint32_t* __restrict__ ws) {
    int b = blockIdx.y;
    int base = blockIdx.x * 256 + threadIdx.x;
    float4 av[K2_APT];
    #pragma unroll
    for (int k = 0; k < K2_APT; ++k)
        av[k] = ((const float4*)anchors)[b * Nn + base + k * K2_STRIDE];
    float rowmax[K2_APT]; int ori[K2_APT]; bool restore[K2_APT];
    #pragma unroll
    for (int k = 0; k < K2_APT; ++k) { rowmax[k] = -1.0f; ori[k] = 0; restore[k] = false; }
    #pragma unroll 4
    for (int t = 0; t < Mn; ++t) {
        float4 tv = ((const float4*)targets)[b * Mn + t];
        float cmf = __uint_as_float(ws[OFF_COLMAX + b * Mn + t]);
        #pragma unroll
        for (int k = 0; k < K2_APT; ++k) {
            float iou = iou_one(av[k].x, av[k].y, av[k].z, av[k].w, tv.x, tv.y, tv.z, tv.w);
            if (iou > rowmax[k]) { rowmax[k] = iou; ori[k] = t; }
            restore[k] = restore[k] || (iou == cmf);
        }
    }
    float sh = sizes[b * 2 + 0], sw = sizes[b * 2 + 1];
    uint32_t key0 = ws[OFF_KEYS + 2 * b], key1 = ws[OFF_KEYS + 2 * b + 1];
    #pragma unroll
    for (int k = 0; k < K2_APT; ++k) {
        int i = base + k * K2_STRIDE;
        bool inside = (av[k].x >= 0.0f) && (av[k].y >= 0.0f) &&
                      (av[k].z <= sw - 1.0f) && (av[k].w <= sh - 1.0f);
        uint32_t cat = 0;  // 0 ignore, 1 neg, 2 pos
        if (inside) {
            if (restore[k] || rowmax[k] >= FG_THR) cat = 2;
            else if (rowmax[k] < BG_THR) cat = 1;
        }
        uint32_t m = rng_m23(key0, key1, (uint32_t)i);
        ws[OFF_PACK + b * Nn + i] = m | (cat << 24);
        if (cat == 2u) {
            uint32_t p = atomicAdd(&ws[OFF_POSCNT + b], 1u);
            if (p < POS_CAP) {
                ws[OFF_PLIST + ((uint32_t)b * POS_CAP + p) * 2 + 0] = m;
                ws[OFF_PLIST + ((uint32_t)b * POS_CAP + p) * 2 + 1] = (uint32_t)i | ((uint32_t)ori[k] << 17);
            }
        } else if (cat == 1u) {
            atomicAdd(&ws[OFF_HIST + b * 1024 + (m >> 13)], 1u);
        }
    }
}

// ------------------- K2.5: find boundary bucket per image (parallel scan) -------------------
__global__ void __launch_bounds__(256) k25_bound(uint32_t* __restrict__ ws) {
    int b = blockIdx.x;
    int t = threadIdx.x;
    __shared__ uint32_t csum[256];
    uint32_t h[4];
    uint32_t sum = 0;
    #pragma unroll
    for (int j = 0; j < 4; ++j) { h[j] = ws[OFF_HIST + b * 1024 + 4 * t + j]; sum += h[j]; }
    csum[t] = sum;
    __syncthreads();
    for (int off = 1; off < 256; off <<= 1) {
        uint32_t mine = csum[t];
        uint32_t add = (t + off < 256) ? csum[t + off] : 0u;
        __syncthreads();
        csum[t] = mine + add;
        __syncthreads();
    }
    uint32_t pc = ws[OFF_POSCNT + b];
    int num_pos = (pc < (uint32_t)NPOSMAX) ? (int)pc : NPOSMAX;
    int k_neg = NPERIM - num_pos;
    uint32_t total = csum[0];
    if ((int)total < k_neg) {
        if (t == 0) {
            ws[OFF_BOUND + b] = 0xFFFFFFFFu;
            ws[OFF_NEED + b] = 0u;
            atomicAdd(&ws[OFF_COUNT], (uint32_t)(num_pos + (int)total));
        }
        return;
    }
    uint32_t incl = csum[t];
    uint32_t next = (t < 255) ? csum[t + 1] : 0u;
    if ((int)incl >= k_neg && (int)next < k_neg) {
        int cum = (int)next;
        int boundary = -1, needed = 0;
        #pragma unroll
        for (int j = 3; j >= 0; --j) {
            int c = (int)h[j];
            if (cum + c >= k_neg) { boundary = 4 * t + j; needed = k_neg - cum; break; }
            cum += c;
        }
        ws[OFF_BOUND + b] = (uint32_t)boundary;
        ws[OFF_NEED + b] = (uint32_t)needed;
        atomicAdd(&ws[OFF_COUNT], (uint32_t)(num_pos + k_neg));
    }
}

// ------------------- K3: BCE sum for clearly-selected negatives; gather boundary -------------------
__global__ void __launch_bounds__(256) k3_neg(const float* __restrict__ logits,
                                              uint32_t* __restrict__ ws) {
    int b = blockIdx.y;
    int i = blockIdx.x * 256 + threadIdx.x;
    int bd = (int)(int32_t)ws[OFF_BOUND + b];
    uint32_t p = ws[OFF_PACK + b * Nn + i];
    uint32_t cat = p >> 24;
    float local = 0.0f;
    if (cat == 1u) {
        uint32_t m = p & 0x7FFFFFu;
        int bk = (int)(m >> 13);
        if (bk > bd) {
            int a = i % An, hw = i / An;
            float l = logits[(b * An + a) * HWn + hw];
            local = fmaxf(l, 0.0f) + log1pf(expf(-fabsf(l)));   // BCE(l, 0)
        } else if (bk == bd) {
            uint32_t q = atomicAdd(&ws[OFF_BNDCNT + b], 1u);
            if (q < BND_CAP) {
                ws[OFF_BLIST + ((uint32_t)b * BND_CAP + q) * 2 + 0] = m;
                ws[OFF_BLIST + ((uint32_t)b * BND_CAP + q) * 2 + 1] = (uint32_t)i;
            }
        }
    }
    __shared__ float red[256];
    red[threadIdx.x] = local;
    __syncthreads();
    for (int s = 128; s > 0; s >>= 1) {
        if ((int)threadIdx.x < s) red[threadIdx.x] += red[threadIdx.x + s];
        __syncthreads();
    }
    if (threadIdx.x == 0 && red[0] != 0.0f) atomicAdd((float*)&ws[OFF_CLS], red[0]);
}

// ------------------- K4: per-image finalize + final divide -------------------
__device__ __forceinline__ bool sel_less(uint2 a, uint2 b) {
    return (a.x > b.x) || (a.x == b.x && a.y < b.y);
}

__device__ void bitonic_sort_shared(uint2* buf, int n) {   // n = pow2
    for (int k = 2; k <= n; k <<= 1) {
        for (int j = k >> 1; j > 0; j >>= 1) {
            for (int t = (int)threadIdx.x; t < n; t += 256) {
                int ixj = t ^ j;
                if (ixj > t) {
                    uint2 x = buf[t], y = buf[ixj];
                    bool up = ((t & k) == 0);
                    bool sw = up ? sel_less(y, x) : sel_less(x, y);
                    if (sw) { buf[t] = y; buf[ixj] = x; }
                }
            }
            __syncthreads();
        }
    }
}

__global__ void __launch_bounds__(256) k4_final(const float* __restrict__ anchors,
                                                const float* __restrict__ targets,
                                                const float* __restrict__ logits,
                                                const float* __restrict__ bregs,
                                                uint32_t* __restrict__ ws,
                                                float* __restrict__ out) {
    int b = blockIdx.x;
    __shared__ uint2 buf[BND_CAP];
    __shared__ float red[256];
    float cls = 0.0f, reg = 0.0f;

    // ----- positives -----
    uint32_t pcu = ws[OFF_POSCNT + b];
    int pc = (pcu < (uint32_t)POS_CAP) ? (int)pcu : POS_CAP;
    const uint32_t* plist = ws + OFF_PLIST + (size_t)b * POS_CAP * 2;
    int psel = (pc < NPOSMAX) ? pc : NPOSMAX;
    bool use_buf = false;
    if (pc > NPOSMAX) {
        int n = (pc < BND_CAP) ? pc : BND_CAP;
        for (int j = (int)threadIdx.x; j < n; j += 256) buf[j] = make_uint2(plist[2*j], plist[2*j+1]);
        int npad = 1; while (npad < n) npad <<= 1;
        for (int j = (int)threadIdx.x; j < npad; j += 256) if (j >= n) buf[j] = make_uint2(0u, 0xFFFFFFFFu);
        __syncthreads();
        bitonic_sort_shared(buf, npad);
        use_buf = true;
        psel = (NPOSMAX < n) ? NPOSMAX : n;
    }
    for (int j = (int)threadIdx.x; j < psel; j += 256) {
        uint32_t packed = use_buf ? buf[j].y : plist[2*j+1];
        int i = (int)(packed & 0x1FFFFu);
        int ori = (int)(packed >> 17);
        int a = i % An, hw = i / An;
        float l = logits[(b * An + a) * HWn + hw];
        cls += fmaxf(l, 0.0f) - l + log1pf(expf(-fabsf(l)));   // BCE(l, 1)
        float4 av = ((const float4*)anchors)[b * Nn + i];
        float4 tv = ((const float4*)targets)[b * Mn + ori];
        float aws = av.z - av.x + 1.0f, ahs = av.w - av.y + 1.0f;
        float axc = av.x + 0.5f * aws, ayc = av.y + 0.5f * ahs;
        float tws = tv.z - tv.x + 1.0f, ths = tv.w - tv.y + 1.0f;
        float txc = tv.x + 0.5f * tws, tyc = tv.y + 0.5f * ths;
        float off0 = (txc - axc) / aws;
        float off1 = (tyc - ayc) / ahs;
        float off2 = logf(tws / aws);
        float off3 = logf(ths / ahs);
        float br0 = bregs[(b * 12 + a * 4 + 0) * HWn + hw];
        float br1 = bregs[(b * 12 + a * 4 + 1) * HWn + hw];
        float br2 = bregs[(b * 12 + a * 4 + 2) * HWn + hw];
        float br3 = bregs[(b * 12 + a * 4 + 3) * HWn + hw];
        float d;
        d = fabsf(br0 - off0); reg += (d < BETA) ? 0.5f * d * d / BETA : d - 0.5f * BETA;
        d = fabsf(br1 - off1); reg += (d < BETA) ? 0.5f * d * d / BETA : d - 0.5f * BETA;
        d = fabsf(br2 - off2); reg += (d < BETA) ? 0.5f * d * d / BETA : d - 0.5f * BETA;
        d = fabsf(br3 - off3); reg += (d < BETA) ? 0.5f * d * d / BETA : d - 0.5f * BETA;
    }
    __syncthreads();

    // ----- boundary-bucket negatives -----
    int need = (int)ws[OFF_NEED + b];
    if (need > 0) {
        uint32_t nbu = ws[OFF_BNDCNT + b];
        int nb = (nbu < (uint32_t)BND_CAP) ? (int)nbu : BND_CAP;
        const uint32_t* blist = ws + OFF_BLIST + (size_t)b * BND_CAP * 2;
        for (int j = (int)threadIdx.x; j < nb; j += 256) buf[j] = make_uint2(blist[2*j], blist[2*j+1]);
        int npad = 1; while (npad < nb) npad <<= 1;
        for (int j = (int)threadIdx.x; j < npad; j += 256) if (j >= nb) buf[j] = make_uint2(0u, 0xFFFFFFFFu);
        __syncthreads();
        bitonic_sort_shared(buf, npad);
        int sel = (need < nb) ? need : nb;
        for (int j = (int)threadIdx.x; j < sel; j += 256) {
            int i = (int)buf[j].y;
            int a = i % An, hw = i / An;
            float l = logits[(b * An + a) * HWn + hw];
            cls += fmaxf(l, 0.0f) + log1pf(expf(-fabsf(l)));   // BCE(l, 0)
        }
    }

    // ----- block reductions -----
    red[threadIdx.x] = cls;
    __syncthreads();
    for (int s = 128; s > 0; s >>= 1) {
        if ((int)threadIdx.x < s) red[threadIdx.x] += red[threadIdx.x + s];
        __syncthreads();
    }
    if (threadIdx.x == 0 && red[0] != 0.0f) atomicAdd((float*)&ws[OFF_CLS], red[0]);
    __syncthreads();
    red[threadIdx.x] = reg;
    __syncthreads();
    for (int s = 128; s > 0; s >>= 1) {
        if ((int)threadIdx.x < s) red[threadIdx.x] += red[threadIdx.x + s];
        __syncthreads();
    }
    if (threadIdx.x == 0) {
        if (red[0] != 0.0f) atomicAdd((float*)&ws[OFF_REG], red[0]);
        __threadfence();
        uint32_t old = atomicAdd(&ws[OFF_DONE], 1u);
        if (old == Bn - 1) {
            float cls_tot = __uint_as_float(atomicAdd(&ws[OFF_CLS], 0u));
            float reg_tot = __uint_as_float(atomicAdd(&ws[OFF_REG], 0u));
            float cnt = (float)atomicAdd(&ws[OFF_COUNT], 0u);
            out[0] = cls_tot / cnt;
            out[1] = reg_tot / cnt;
        }
    }
}

extern "C" void kernel_launch(void* const* d_in, const int* in_sizes, int n_in,
                              void* d_out, int out_size, void* d_ws, size_t ws_size,
                              hipStream_t stream) {
    const float* anchors = (const float*)d_in[0];   // [B, N, 4]
    const float* logits  = (const float*)d_in[1];   // [B, A, H, W]
    const float* bregs   = (const float*)d_in[2];   // [B, 4A, H, W]
    const float* sizes   = (const float*)d_in[3];   // [B, 2]
    const float* targets = (const float*)d_in[4];   // [B, M, 4]
    float* out = (float*)d_out;
    uint32_t* ws = (uint32_t*)d_ws;

    k0_init<<<dim3(64), dim3(256), 0, stream>>>(ws);
    k1_colmax<<<dim3(K1_BLOCKS, Bn), dim3(256), 0, stream>>>(anchors, targets, ws);
    k2_cat<<<dim3(K2_BLOCKS, Bn), dim3(256), 0, stream>>>(anchors, targets, sizes, ws);
    k25_bound<<<dim3(Bn), dim3(256), 0, stream>>>(ws);
    k3_neg<<<dim3(Nn / 256, Bn), dim3(256), 0, stream>>>(logits, ws);
    k4_final<<<dim3(Bn), dim3(256), 0, stream>>>(anchors, targets, logits, bregs, ws, out);
}

// Round 6
// 161.747 us; speedup vs baseline: 1.1130x; 1.1130x over previous
//
#include <hip/hip_runtime.h>
#include <stdint.h>

#define Bn 4
#define An 3
#define Hn 168
#define Wn 256
#define Mn 32
#define HWn (Hn*Wn)
#define Nn (HWn*An)          // 129024
#define POS_CAP 8192
#define BND_CAP 2048
#define NPERIM 256
#define NPOSMAX 128
#define FG_THR 0.7f
#define BG_THR 0.3f
#define BETA (1.0f/9.0f)

// ---- workspace layout (uint32 word offsets) ----
#define OFF_KEYS   0            // Bn*2 (written in k0, outside zero range)
#define OFF_COLMAX 8            // Bn*Mn = 128 (float bits, atomicMax)
#define OFF_POSCNT 136          // Bn
#define OFF_BNDCNT 140          // Bn
#define OFF_BOUND  144          // Bn (int32, -1 = all negatives selected)
#define OFF_NEED   148          // Bn
#define OFF_COUNT  152          // 1 (uint)
#define OFF_CLS    153          // 1 (float bits)
#define OFF_REG    154          // 1 (float bits)
#define OFF_DONE   155          // 1 (uint)
#define ZERO_BEG   8
#define ZERO_END   160
#define OFF_PACK   4256         // Bn*Nn  (m | cat<<24)       -> 520352
#define OFF_PLIST  520352       // Bn*POS_CAP*2               -> 585888
#define OFF_BLIST  585888       // Bn*BND_CAP*2               -> 602272
#define OFF_PHIST  602272       // Bn*K2_BLOCKS*1024 = 516096 -> 1118368 (~4.5MB)

// ------------------- threefry2x32 (20 rounds) -------------------
__device__ __forceinline__ uint32_t rotl32(uint32_t v, int n) { return (v << n) | (v >> (32 - n)); }

__device__ __forceinline__ void tf2x32(uint32_t k0, uint32_t k1, uint32_t x0, uint32_t x1,
                                       uint32_t& o0, uint32_t& o1) {
    uint32_t k2 = k0 ^ k1 ^ 0x1BD11BDAu;
    x0 += k0; x1 += k1;
    x0 += x1; x1 = rotl32(x1, 13); x1 ^= x0;
    x0 += x1; x1 = rotl32(x1, 15); x1 ^= x0;
    x0 += x1; x1 = rotl32(x1, 26); x1 ^= x0;
    x0 += x1; x1 = rotl32(x1, 6);  x1 ^= x0;
    x0 += k1; x1 += k2 + 1u;
    x0 += x1; x1 = rotl32(x1, 17); x1 ^= x0;
    x0 += x1; x1 = rotl32(x1, 29); x1 ^= x0;
    x0 += x1; x1 = rotl32(x1, 16); x1 ^= x0;
    x0 += x1; x1 = rotl32(x1, 24); x1 ^= x0;
    x0 += k2; x1 += k0 + 2u;
    x0 += x1; x1 = rotl32(x1, 13); x1 ^= x0;
    x0 += x1; x1 = rotl32(x1, 15); x1 ^= x0;
    x0 += x1; x1 = rotl32(x1, 26); x1 ^= x0;
    x0 += x1; x1 = rotl32(x1, 6);  x1 ^= x0;
    x0 += k0; x1 += k1 + 3u;
    x0 += x1; x1 = rotl32(x1, 17); x1 ^= x0;
    x0 += x1; x1 = rotl32(x1, 29); x1 ^= x0;
    x0 += x1; x1 = rotl32(x1, 16); x1 ^= x0;
    x0 += x1; x1 = rotl32(x1, 24); x1 ^= x0;
    x0 += k1; x1 += k2 + 4u;
    x0 += x1; x1 = rotl32(x1, 13); x1 ^= x0;
    x0 += x1; x1 = rotl32(x1, 15); x1 ^= x0;
    x0 += x1; x1 = rotl32(x1, 26); x1 ^= x0;
    x0 += x1; x1 = rotl32(x1, 6);  x1 ^= x0;
    x0 += k2; x1 += k0 + 5u;
    o0 = x0; o1 = x1;
}

__device__ __forceinline__ uint32_t rng_m23(uint32_t k0, uint32_t k1, uint32_t i) {
    uint32_t o0, o1;
    tf2x32(k0, k1, 0u, i, o0, o1);
    return (o0 ^ o1) >> 9;
}

// ------------------- IoU (shared by k1/k2 for bit-identical values) -------------------
__device__ __forceinline__ float iou_one(float a0, float a1, float a2, float a3,
                                         float t0, float t1, float t2, float t3) {
    float xtl = fmaxf(a0, t0), ytl = fmaxf(a1, t1);
    float xrb = fminf(a2, t2), yrb = fminf(a3, t3);
    float iw = fmaxf(xrb - xtl + 1.0f, 0.0f);
    float ih = fmaxf(yrb - ytl + 1.0f, 0.0f);
    float inter = iw * ih;
    float area1 = (a2 - a0 + 1.0f) * (a3 - a1 + 1.0f);
    float area2 = (t2 - t0 + 1.0f) * (t3 - t1 + 1.0f);
    return inter * __builtin_amdgcn_rcpf(area1 + area2 - inter);
}

// ------------------- K0: zero control words, derive per-image keys -------------------
__global__ void k0_init(uint32_t* __restrict__ ws) {
    int t = blockIdx.x * blockDim.x + threadIdx.x;
    for (int j = ZERO_BEG + t; j < ZERO_END; j += gridDim.x * blockDim.x) ws[j] = 0u;
    if (t == 0) {
        for (int b = 0; b < Bn; ++b) {
            uint32_t o0, o1;
            tf2x32(0u, 42u, 0u, (uint32_t)b, o0, o1);
            ws[OFF_KEYS + 2*b] = o0; ws[OFF_KEYS + 2*b + 1] = o1;
        }
    }
}

// ------------------- K1: per-target column max IoU -------------------
#define K1_APT 4
#define K1_BLOCKS 126
#define K1_STRIDE (K1_BLOCKS * 256)    // 32256
__global__ void __launch_bounds__(256) k1_colmax(const float* __restrict__ anchors,
                                                 const float* __restrict__ targets,
                                                 uint32_t* __restrict__ ws) {
    int b = blockIdx.y;
    __shared__ float part[4][Mn];
    int base = blockIdx.x * 256 + threadIdx.x;
    float4 a[K1_APT];
    #pragma unroll
    for (int k = 0; k < K1_APT; ++k)
        a[k] = ((const float4*)anchors)[b * Nn + base + k * K1_STRIDE];
    float cm[Mn];
    #pragma unroll 4
    for (int t = 0; t < Mn; ++t) {
        float4 tv = ((const float4*)targets)[b * Mn + t];
        float m0 = 0.0f;
        #pragma unroll
        for (int k = 0; k < K1_APT; ++k)
            m0 = fmaxf(m0, iou_one(a[k].x, a[k].y, a[k].z, a[k].w, tv.x, tv.y, tv.z, tv.w));
        cm[t] = m0;
    }
    #pragma unroll
    for (int t = 0; t < Mn; ++t) {
        #pragma unroll
        for (int o = 32; o > 0; o >>= 1) cm[t] = fmaxf(cm[t], __shfl_xor(cm[t], o, 64));
    }
    int wid = threadIdx.x >> 6, lane = threadIdx.x & 63;
    if (lane == 0) {
        #pragma unroll
        for (int t = 0; t < Mn; ++t) part[wid][t] = cm[t];
    }
    __syncthreads();
    if (threadIdx.x < Mn) {
        float v = fmaxf(fmaxf(part[0][threadIdx.x], part[1][threadIdx.x]),
                        fmaxf(part[2][threadIdx.x], part[3][threadIdx.x]));
        atomicMax(&ws[OFF_COLMAX + b * Mn + threadIdx.x], __float_as_uint(v));
    }
}

// ------------------- K2: categorize, RNG, LDS histogram, positive list -------------------
// APT=4 (measured fastest: 42us vs 51-52 at APT=1/2 — ILP beats occupancy here).
// Histogram via per-block LDS + private global slice (plain coalesced stores):
// eliminates the ~180k scattered global atomics that stalled R3-R5 at ~45us.
#define K2_APT 4
#define K2_BLOCKS 126
#define K2_STRIDE (K2_BLOCKS * 256)    // 32256
__global__ void __launch_bounds__(256) k2_cat(const float* __restrict__ anchors,
                                              const float* __restrict__ targets,
                                              const float* __restrict__ sizes,
                                              uint32_t* __restrict__ ws) {
    int b = blockIdx.y;
    __shared__ uint32_t lh[1024];
    #pragma unroll
    for (int j = 0; j < 4; ++j) lh[threadIdx.x + 256 * j] = 0u;
    __syncthreads();
    int base = blockIdx.x * 256 + threadIdx.x;
    float4 av[K2_APT];
    #pragma unroll
    for (int k = 0; k < K2_APT; ++k)
        av[k] = ((const float4*)anchors)[b * Nn + base + k * K2_STRIDE];
    float rowmax[K2_APT]; int ori[K2_APT]; bool restore[K2_APT];
    #pragma unroll
    for (int k = 0; k < K2_APT; ++k) { rowmax[k] = -1.0f; ori[k] = 0; restore[k] = false; }
    #pragma unroll 4
    for (int t = 0; t < Mn; ++t) {
        float4 tv = ((const float4*)targets)[b * Mn + t];
        float cmf = __uint_as_float(ws[OFF_COLMAX + b * Mn + t]);
        #pragma unroll
        for (int k = 0; k < K2_APT; ++k) {
            float iou = iou_one(av[k].x, av[k].y, av[k].z, av[k].w, tv.x, tv.y, tv.z, tv.w);
            if (iou > rowmax[k]) { rowmax[k] = iou; ori[k] = t; }
            restore[k] = restore[k] || (iou == cmf);
        }
    }
    float sh = sizes[b * 2 + 0], sw = sizes[b * 2 + 1];
    uint32_t key0 = ws[OFF_KEYS + 2 * b], key1 = ws[OFF_KEYS + 2 * b + 1];
    #pragma unroll
    for (int k = 0; k < K2_APT; ++k) {
        int i = base + k * K2_STRIDE;
        bool inside = (av[k].x >= 0.0f) && (av[k].y >= 0.0f) &&
                      (av[k].z <= sw - 1.0f) && (av[k].w <= sh - 1.0f);
        uint32_t cat = 0;  // 0 ignore, 1 neg, 2 pos
        if (inside) {
            if (restore[k] || rowmax[k] >= FG_THR) cat = 2;
            else if (rowmax[k] < BG_THR) cat = 1;
        }
        uint32_t m = rng_m23(key0, key1, (uint32_t)i);
        ws[OFF_PACK + b * Nn + i] = m | (cat << 24);
        if (cat == 2u) {
            uint32_t p = atomicAdd(&ws[OFF_POSCNT + b], 1u);
            if (p < POS_CAP) {
                ws[OFF_PLIST + ((uint32_t)b * POS_CAP + p) * 2 + 0] = m;
                ws[OFF_PLIST + ((uint32_t)b * POS_CAP + p) * 2 + 1] = (uint32_t)i | ((uint32_t)ori[k] << 17);
            }
        } else if (cat == 1u) {
            atomicAdd(&lh[m >> 13], 1u);   // LDS atomic — cheap
        }
    }
    __syncthreads();
    // write private slice: fully written (no pre-zero needed), coalesced uint4
    uint32_t* slice = ws + OFF_PHIST + ((size_t)b * K2_BLOCKS + blockIdx.x) * 1024;
    #pragma unroll
    for (int j = 0; j < 4; ++j) {
        int idx = threadIdx.x + 256 * j;
        slice[idx] = lh[idx];
    }
}

// ------------------- K2.5: reduce slices + find boundary bucket -------------------
__global__ void __launch_bounds__(256) k25_bound(uint32_t* __restrict__ ws) {
    int b = blockIdx.x;
    int t = threadIdx.x;
    __shared__ uint32_t csum[256];
    uint4 h = make_uint4(0, 0, 0, 0);
    const uint32_t* ph = ws + OFF_PHIST + (size_t)b * K2_BLOCKS * 1024;
    for (int s = 0; s < K2_BLOCKS; ++s) {
        uint4 v = ((const uint4*)(ph + (size_t)s * 1024))[t];
        h.x += v.x; h.y += v.y; h.z += v.z; h.w += v.w;
    }
    uint32_t sum = h.x + h.y + h.z + h.w;
    csum[t] = sum;
    __syncthreads();
    for (int off = 1; off < 256; off <<= 1) {
        uint32_t mine = csum[t];
        uint32_t add = (t + off < 256) ? csum[t + off] : 0u;
        __syncthreads();
        csum[t] = mine + add;
        __syncthreads();
    }
    uint32_t pc = ws[OFF_POSCNT + b];
    int num_pos = (pc < (uint32_t)NPOSMAX) ? (int)pc : NPOSMAX;
    int k_neg = NPERIM - num_pos;
    uint32_t total = csum[0];
    if ((int)total < k_neg) {
        if (t == 0) {
            ws[OFF_BOUND + b] = 0xFFFFFFFFu;
            ws[OFF_NEED + b] = 0u;
            atomicAdd(&ws[OFF_COUNT], (uint32_t)(num_pos + (int)total));
        }
        return;
    }
    uint32_t incl = csum[t];
    uint32_t next = (t < 255) ? csum[t + 1] : 0u;
    if ((int)incl >= k_neg && (int)next < k_neg) {
        int cum = (int)next;
        uint32_t hv[4] = { h.x, h.y, h.z, h.w };
        int boundary = -1, needed = 0;
        #pragma unroll
        for (int j = 3; j >= 0; --j) {
            int c = (int)hv[j];
            if (cum + c >= k_neg) { boundary = 4 * t + j; needed = k_neg - cum; break; }
            cum += c;
        }
        ws[OFF_BOUND + b] = (uint32_t)boundary;
        ws[OFF_NEED + b] = (uint32_t)needed;
        atomicAdd(&ws[OFF_COUNT], (uint32_t)(num_pos + k_neg));
    }
}

// ------------------- K3: BCE sum for clearly-selected negatives; gather boundary -------------------
__global__ void __launch_bounds__(256) k3_neg(const float* __restrict__ logits,
                                              uint32_t* __restrict__ ws) {
    int b = blockIdx.y;
    int i = blockIdx.x * 256 + threadIdx.x;
    int bd = (int)(int32_t)ws[OFF_BOUND + b];
    uint32_t p = ws[OFF_PACK + b * Nn + i];
    uint32_t cat = p >> 24;
    float local = 0.0f;
    if (cat == 1u) {
        uint32_t m = p & 0x7FFFFFu;
        int bk = (int)(m >> 13);
        if (bk > bd) {
            int a = i % An, hw = i / An;
            float l = logits[(b * An + a) * HWn + hw];
            local = fmaxf(l, 0.0f) + log1pf(expf(-fabsf(l)));   // BCE(l, 0)
        } else if (bk == bd) {
            uint32_t q = atomicAdd(&ws[OFF_BNDCNT + b], 1u);
            if (q < BND_CAP) {
                ws[OFF_BLIST + ((uint32_t)b * BND_CAP + q) * 2 + 0] = m;
                ws[OFF_BLIST + ((uint32_t)b * BND_CAP + q) * 2 + 1] = (uint32_t)i;
            }
        }
    }
    __shared__ float red[256];
    red[threadIdx.x] = local;
    __syncthreads();
    for (int s = 128; s > 0; s >>= 1) {
        if ((int)threadIdx.x < s) red[threadIdx.x] += red[threadIdx.x + s];
        __syncthreads();
    }
    if (threadIdx.x == 0 && red[0] != 0.0f) atomicAdd((float*)&ws[OFF_CLS], red[0]);
}

// ------------------- K4: per-image finalize + final divide -------------------
__device__ __forceinline__ bool sel_less(uint2 a, uint2 b) {
    return (a.x > b.x) || (a.x == b.x && a.y < b.y);
}

__device__ void bitonic_sort_shared(uint2* buf, int n) {   // n = pow2
    for (int k = 2; k <= n; k <<= 1) {
        for (int j = k >> 1; j > 0; j >>= 1) {
            for (int t = (int)threadIdx.x; t < n; t += 256) {
                int ixj = t ^ j;
                if (ixj > t) {
                    uint2 x = buf[t], y = buf[ixj];
                    bool up = ((t & k) == 0);
                    bool sw = up ? sel_less(y, x) : sel_less(x, y);
                    if (sw) { buf[t] = y; buf[ixj] = x; }
                }
            }
            __syncthreads();
        }
    }
}

__global__ void __launch_bounds__(256) k4_final(const float* __restrict__ anchors,
                                                const float* __restrict__ targets,
                                                const float* __restrict__ logits,
                                                const float* __restrict__ bregs,
                                                uint32_t* __restrict__ ws,
                                                float* __restrict__ out) {
    int b = blockIdx.x;
    __shared__ uint2 buf[BND_CAP];
    __shared__ float red[256];
    float cls = 0.0f, reg = 0.0f;

    // ----- positives -----
    uint32_t pcu = ws[OFF_POSCNT + b];
    int pc = (pcu < (uint32_t)POS_CAP) ? (int)pcu : POS_CAP;
    const uint32_t* plist = ws + OFF_PLIST + (size_t)b * POS_CAP * 2;
    int psel = (pc < NPOSMAX) ? pc : NPOSMAX;
    bool use_buf = false;
    if (pc > NPOSMAX) {
        int n = (pc < BND_CAP) ? pc : BND_CAP;
        for (int j = (int)threadIdx.x; j < n; j += 256) buf[j] = make_uint2(plist[2*j], plist[2*j+1]);
        int npad = 1; while (npad < n) npad <<= 1;
        for (int j = (int)threadIdx.x; j < npad; j += 256) if (j >= n) buf[j] = make_uint2(0u, 0xFFFFFFFFu);
        __syncthreads();
        bitonic_sort_shared(buf, npad);
        use_buf = true;
        psel = (NPOSMAX < n) ? NPOSMAX : n;
    }
    for (int j = (int)threadIdx.x; j < psel; j += 256) {
        uint32_t packed = use_buf ? buf[j].y : plist[2*j+1];
        int i = (int)(packed & 0x1FFFFu);
        int ori = (int)(packed >> 17);
        int a = i % An, hw = i / An;
        float l = logits[(b * An + a) * HWn + hw];
        cls += fmaxf(l, 0.0f) - l + log1pf(expf(-fabsf(l)));   // BCE(l, 1)
        float4 av = ((const float4*)anchors)[b * Nn + i];
        float4 tv = ((const float4*)targets)[b * Mn + ori];
        float aws = av.z - av.x + 1.0f, ahs = av.w - av.y + 1.0f;
        float axc = av.x + 0.5f * aws, ayc = av.y + 0.5f * ahs;
        float tws = tv.z - tv.x + 1.0f, ths = tv.w - tv.y + 1.0f;
        float txc = tv.x + 0.5f * tws, tyc = tv.y + 0.5f * ths;
        float off0 = (txc - axc) / aws;
        float off1 = (tyc - ayc) / ahs;
        float off2 = logf(tws / aws);
        float off3 = logf(ths / ahs);
        float br0 = bregs[(b * 12 + a * 4 + 0) * HWn + hw];
        float br1 = bregs[(b * 12 + a * 4 + 1) * HWn + hw];
        float br2 = bregs[(b * 12 + a * 4 + 2) * HWn + hw];
        float br3 = bregs[(b * 12 + a * 4 + 3) * HWn + hw];
        float d;
        d = fabsf(br0 - off0); reg += (d < BETA) ? 0.5f * d * d / BETA : d - 0.5f * BETA;
        d = fabsf(br1 - off1); reg += (d < BETA) ? 0.5f * d * d / BETA : d - 0.5f * BETA;
        d = fabsf(br2 - off2); reg += (d < BETA) ? 0.5f * d * d / BETA : d - 0.5f * BETA;
        d = fabsf(br3 - off3); reg += (d < BETA) ? 0.5f * d * d / BETA : d - 0.5f * BETA;
    }
    __syncthreads();

    // ----- boundary-bucket negatives -----
    int need = (int)ws[OFF_NEED + b];
    if (need > 0) {
        uint32_t nbu = ws[OFF_BNDCNT + b];
        int nb = (nbu < (uint32_t)BND_CAP) ? (int)nbu : BND_CAP;
        const uint32_t* blist = ws + OFF_BLIST + (size_t)b * BND_CAP * 2;
        for (int j = (int)threadIdx.x; j < nb; j += 256) buf[j] = make_uint2(blist[2*j], blist[2*j+1]);
        int npad = 1; while (npad < nb) npad <<= 1;
        for (int j = (int)threadIdx.x; j < npad; j += 256) if (j >= nb) buf[j] = make_uint2(0u, 0xFFFFFFFFu);
        __syncthreads();
        bitonic_sort_shared(buf, npad);
        int sel = (need < nb) ? need : nb;
        for (int j = (int)threadIdx.x; j < sel; j += 256) {
            int i = (int)buf[j].y;
            int a = i % An, hw = i / An;
            float l = logits[(b * An + a) * HWn + hw];
            cls += fmaxf(l, 0.0f) + log1pf(expf(-fabsf(l)));   // BCE(l, 0)
        }
    }

    // ----- block reductions -----
    red[threadIdx.x] = cls;
    __syncthreads();
    for (int s = 128; s > 0; s >>= 1) {
        if ((int)threadIdx.x < s) red[threadIdx.x] += red[threadIdx.x + s];
        __syncthreads();
    }
    if (threadIdx.x == 0 && red[0] != 0.0f) atomicAdd((float*)&ws[OFF_CLS], red[0]);
    __syncthreads();
    red[threadIdx.x] = reg;
    __syncthreads();
    for (int s = 128; s > 0; s >>= 1) {
        if ((int)threadIdx.x < s) red[threadIdx.x] += red[threadIdx.x + s];
        __syncthreads();
    }
    if (threadIdx.x == 0) {
        if (red[0] != 0.0f) atomicAdd((float*)&ws[OFF_REG], red[0]);
        __threadfence();
        uint32_t old = atomicAdd(&ws[OFF_DONE], 1u);
        if (old == Bn - 1) {
            float cls_tot = __uint_as_float(atomicAdd(&ws[OFF_CLS], 0u));
            float reg_tot = __uint_as_float(atomicAdd(&ws[OFF_REG], 0u));
            float cnt = (float)atomicAdd(&ws[OFF_COUNT], 0u);
            out[0] = cls_tot / cnt;
            out[1] = reg_tot / cnt;
        }
    }
}

extern "C" void kernel_launch(void* const* d_in, const int* in_sizes, int n_in,
                              void* d_out, int out_size, void* d_ws, size_t ws_size,
                              hipStream_t stream) {
    const float* anchors = (const float*)d_in[0];   // [B, N, 4]
    const float* logits  = (const float*)d_in[1];   // [B, A, H, W]
    const float* bregs   = (const float*)d_in[2];   // [B, 4A, H, W]
    const float* sizes   = (const float*)d_in[3];   // [B, 2]
    const float* targets = (const float*)d_in[4];   // [B, M, 4]
    float* out = (float*)d_out;
    uint32_t* ws = (uint32_t*)d_ws;

    k0_init<<<dim3(64), dim3(256), 0, stream>>>(ws);
    k1_colmax<<<dim3(K1_BLOCKS, Bn), dim3(256), 0, stream>>>(anchors, targets, ws);
    k2_cat<<<dim3(K2_BLOCKS, Bn), dim3(256), 0, stream>>>(anchors, targets, sizes, ws);
    k25_bound<<<dim3(Bn), dim3(256), 0, stream>>>(ws);
    k3_neg<<<dim3(Nn / 256, Bn), dim3(256), 0, stream>>>(logits, ws);
    k4_final<<<dim3(Bn), dim3(256), 0, stream>>>(anchors, targets, logits, bregs, ws, out);
}